// Round 3
// baseline (1060.785 us; speedup 1.0000x reference)
//
#include <hip/hip_runtime.h>
#include <hip/hip_bf16.h>
#include <stdint.h>

// Problem constants
#define N_TOK 4096
#define DDIM  2048
#define VOCAB 50257
#define IGNORE_INDEX (-100)

// 8-phase 256x256 tiling (main kernel)
#define BM 256                         // vocab tile (MFMA M)
#define BT 256                         // token tile (MFMA N)
#define BK 64
#define NT (DDIM / BK)                 // 32 K-tiles
#define VCH ((VOCAB + BM - 1) / BM)    // 197
#define VP  (VCH * BM)                 // 50432 padded vocab
#define RT  (N_TOK / BT)               // 16 row tiles

// Fallback (round-1) tiling
#define FB_B 128
#define FB_VCH ((VOCAB + FB_B - 1) / FB_B)  // 393
#define FB_RT (N_TOK / FB_B)                // 32

typedef float f32x4 __attribute__((ext_vector_type(4)));
typedef short bf16x8 __attribute__((ext_vector_type(8)));

__device__ __forceinline__ uint32_t pack2bf(float a, float b) {
  uint32_t ua = __float_as_uint(a);
  uint32_t ub = __float_as_uint(b);
  uint32_t ra = (ua + 0x7fffu + ((ua >> 16) & 1u)) >> 16;
  uint32_t rb = (ub + 0x7fffu + ((ub >> 16) & 1u)) & 0xffff0000u;
  return (ra & 0xffffu) | rb;
}

__device__ __forceinline__ void gload_lds16(const void* g, void* l) {
  __builtin_amdgcn_global_load_lds(
      (const __attribute__((address_space(1))) uint32_t*)g,
      (__attribute__((address_space(3))) uint32_t*)l, 16, 0, 0);
}

#define WGBAR() do { asm volatile("" ::: "memory"); \
                     __builtin_amdgcn_s_barrier(); \
                     asm volatile("" ::: "memory"); } while (0)

// ---------------------------------------------------------------------------
// Prep 1: x fp32[N][D] -> bf16[N][D]
// ---------------------------------------------------------------------------
__global__ __launch_bounds__(256) void convert_x(const float* __restrict__ x,
                                                 ushort* __restrict__ xb) {
  int t = blockIdx.x * 256 + threadIdx.x;
  float4 f0 = ((const float4*)x)[(size_t)t * 2];
  float4 f1 = ((const float4*)x)[(size_t)t * 2 + 1];
  uint4 pk;
  pk.x = pack2bf(f0.x, f0.y); pk.y = pack2bf(f0.z, f0.w);
  pk.z = pack2bf(f1.x, f1.y); pk.w = pack2bf(f1.z, f1.w);
  ((uint4*)xb)[t] = pk;
}

// ---------------------------------------------------------------------------
// Prep 2: w fp32[D][V] -> wt bf16[VP][D] (transpose, zero-pad v >= VOCAB)
// ---------------------------------------------------------------------------
__global__ __launch_bounds__(256) void transpose_w(const float* __restrict__ w,
                                                   ushort* __restrict__ wt) {
  __shared__ float t[64][65];
  const int vb = blockIdx.x * 64;   // VP/64 = 788 blocks
  const int kb = blockIdx.y * 64;   // D/64  = 32 blocks
  const int tid = threadIdx.x;
  const int tv = tid & 63, tk4 = tid >> 6;
  #pragma unroll
  for (int i = 0; i < 16; ++i) {
    int kl = tk4 + i * 4;
    int v = vb + tv;
    float val = (v < VOCAB) ? w[(size_t)(kb + kl) * VOCAB + v] : 0.f;
    t[kl][tv] = val;
  }
  __syncthreads();
  const int k2 = tid & 31, v8 = tid >> 5;
  #pragma unroll
  for (int i = 0; i < 8; ++i) {
    int vl = v8 + i * 8;
    uint32_t pk = pack2bf(t[k2 * 2][vl], t[k2 * 2 + 1][vl]);
    *(uint32_t*)(wt + (size_t)(vb + vl) * DDIM + kb + k2 * 2) = pk;
  }
}

// ---------------------------------------------------------------------------
// Main: 256^2 8-phase bf16 GEMM (T2 swizzle + T3/T4 counted vmcnt + T5
// setprio) fused with per-(row, V-chunk) online-softmax partials.
// A = wt[VP][D] (vocab-major), B = xb[N][D] (token-major).
// 8 waves: wm = vocab half (128 rows), wq = token quarter (64 cols).
// Schedule per K-tile t (4 phases); staging fills buf[(t+1)&1] halves
// A1,B0,B1 in ph1-3 and buf[(t)&1] gets tile t+2's A0 in ph4 (safe: all
// reads of buf[t] complete by ph3's end barrier). vmcnt(2) once per tile.
// ---------------------------------------------------------------------------
__global__ __launch_bounds__(512, 2) void lmhead8(
    const ushort* __restrict__ wt, const ushort* __restrict__ xb,
    const int* __restrict__ tgt,
    float2* __restrict__ partial, float* __restrict__ tlogit)
{
  __shared__ char lds[131072];        // [2 bufs][A 32K | B 32K]
  __shared__ float2 stats[2][BT];

  const int bid = blockIdx.x;
  const int v = bid >> 4;             // chunk-major: 16 row-tiles share panel
  const int r = bid & 15;
  const int v0 = v * BM;
  const int m0 = r * BT;
  const int tid = threadIdx.x;
  const int lane = tid & 63;
  const int wid = tid >> 6;
  const int wm = wid & 1;             // vocab half  (A rows wm*128..+128)
  const int wq = wid >> 1;            // token quarter (B rows wq*64..+64)
  const int lr = lane & 15, lk = lane >> 4;

  // staging lane mapping: 1KB chunk = 8 rows x 128B; source pre-swizzled
  const int srow = lane >> 3;
  const int scol = (lane & 7) ^ srow;
  const ushort* wsrcb = wt + (size_t)(v0 + srow) * DDIM + scol * 8;
  const ushort* xsrcb = xb + (size_t)(m0 + srow) * DDIM + scol * 8;

  // ds_read bases (XOR applied per-access, after adding ks*64)
  const int a_base = (wm * 128 + lr) * 128 + lk * 16;
  const int b_base = (wq * 64 + lr) * 128 + lk * 16;
  const int xm = (lr & 7) << 4;

  f32x4 acc[8][4];
  #pragma unroll
  for (int i = 0; i < 8; ++i)
    #pragma unroll
    for (int j = 0; j < 4; ++j) acc[i][j] = (f32x4)0.f;
  bf16x8 af[4][2], bf[4][2];

  // stage one half-tile (128 rows) of operand into buf[T&1]: 2 chunks/wave
  auto stageA = [&](int T, int h) {
    char* dst = lds + (T & 1) * 65536;
    int g = h * 16 + 2 * wid;
    const ushort* s = wsrcb + (size_t)g * 8 * DDIM + (size_t)T * BK;
    gload_lds16(s, dst + g * 1024);
    gload_lds16(s + (size_t)8 * DDIM, dst + g * 1024 + 1024);
  };
  auto stageB = [&](int T, int h) {
    char* dst = lds + (T & 1) * 65536 + 32768;
    int g = h * 16 + 2 * wid;
    const ushort* s = xsrcb + (size_t)g * 8 * DDIM + (size_t)T * BK;
    gload_lds16(s, dst + g * 1024);
    gload_lds16(s + (size_t)8 * DDIM, dst + g * 1024 + 1024);
  };

#define QUAD(R0, C0) do { \
    __builtin_amdgcn_s_setprio(1); \
    _Pragma("unroll") \
    for (int f_ = 0; f_ < 4; ++f_) \
      _Pragma("unroll") \
      for (int c_ = 0; c_ < 2; ++c_) \
        _Pragma("unroll") \
        for (int ks_ = 0; ks_ < 2; ++ks_) \
          acc[(R0) + f_][(C0) + c_] = __builtin_amdgcn_mfma_f32_16x16x32_bf16( \
              af[f_][ks_], bf[(C0) + c_][ks_], acc[(R0) + f_][(C0) + c_], 0, 0, 0); \
    __builtin_amdgcn_s_setprio(0); \
  } while (0)

  // ---- prologue: tile0 all 4 halves + tile1 A0; wait tile0 (leave 2) ----
  stageA(0, 0); stageA(0, 1); stageB(0, 0); stageB(0, 1); stageA(1, 0);
  asm volatile("s_waitcnt vmcnt(2)" ::: "memory");
  WGBAR();

  for (int t = 0; t < NT; ++t) {
    char* LA = lds + (t & 1) * 65536;
    char* LB = LA + 32768;
    const int Tn = (t + 1) & (NT - 1);    // wraps at end: dummy re-stage, safe
    const int Tn2 = (t + 2) & (NT - 1);

    // ---- phase 1: read A rows0-3 + B cols0-1; stage t+1 A1 ----
    #pragma unroll
    for (int f = 0; f < 4; ++f)
      #pragma unroll
      for (int ks = 0; ks < 2; ++ks)
        af[f][ks] = *(const bf16x8*)(LA + ((a_base + f * 2048 + ks * 64) ^ xm));
    #pragma unroll
    for (int c = 0; c < 2; ++c)
      #pragma unroll
      for (int ks = 0; ks < 2; ++ks)
        bf[c][ks] = *(const bf16x8*)(LB + ((b_base + c * 2048 + ks * 64) ^ xm));
    stageA(Tn, 1);
    WGBAR();
    QUAD(0, 0);
    WGBAR();

    // ---- phase 2: read B cols2-3; stage t+1 B0 ----
    #pragma unroll
    for (int c = 2; c < 4; ++c)
      #pragma unroll
      for (int ks = 0; ks < 2; ++ks)
        bf[c][ks] = *(const bf16x8*)(LB + ((b_base + c * 2048 + ks * 64) ^ xm));
    stageB(Tn, 0);
    WGBAR();
    QUAD(0, 2);
    WGBAR();

    // ---- phase 3: read A rows4-7; stage t+1 B1 ----
    #pragma unroll
    for (int f = 0; f < 4; ++f)
      #pragma unroll
      for (int ks = 0; ks < 2; ++ks)
        af[f][ks] = *(const bf16x8*)(LA + ((a_base + (f + 4) * 2048 + ks * 64) ^ xm));
    stageB(Tn, 1);
    WGBAR();
    QUAD(4, 0);
    WGBAR();

    // ---- phase 4: stage t+2 A0 (buf[t&1]: reads done at ph3 barrier) ----
    stageA(Tn2, 0);
    WGBAR();
    QUAD(4, 2);
    asm volatile("s_waitcnt vmcnt(2)" ::: "memory");  // tile t+1 fully landed
    WGBAR();
  }
  asm volatile("s_waitcnt vmcnt(0)" ::: "memory");
  __syncthreads();

  // ---- epilogue: per-token max / sum-exp over this wave's 128 vocab rows ----
  // C/D frag layout: vocab = lk*4 + rg, token = lr (round-1/2 verified)
  #pragma unroll
  for (int c = 0; c < 4; ++c) {
    const int m_g = m0 + wq * 64 + c * 16 + lr;
    float vmax = -INFINITY;
    #pragma unroll
    for (int f = 0; f < 8; ++f) {
      const int nb = v0 + wm * 128 + f * 16 + lk * 4;
      #pragma unroll
      for (int rg = 0; rg < 4; ++rg)
        if (nb + rg < VOCAB) vmax = fmaxf(vmax, acc[f][c][rg]);
    }
    vmax = fmaxf(vmax, __shfl_xor(vmax, 16, 64));
    vmax = fmaxf(vmax, __shfl_xor(vmax, 32, 64));
    const int tg = tgt[m_g];
    float ssum = 0.f;
    #pragma unroll
    for (int f = 0; f < 8; ++f) {
      const int nb = v0 + wm * 128 + f * 16 + lk * 4;
      #pragma unroll
      for (int rg = 0; rg < 4; ++rg) {
        float val = acc[f][c][rg];
        if (nb + rg < VOCAB) ssum += __expf(val - vmax);
        if (nb + rg == tg) tlogit[m_g] = val;
      }
    }
    ssum += __shfl_xor(ssum, 16, 64);
    ssum += __shfl_xor(ssum, 32, 64);
    if (lk == 0) stats[wm][wq * 64 + c * 16 + lr] = make_float2(vmax, ssum);
  }
  __syncthreads();
  if (tid < BT) {
    float2 a = stats[0][tid], b = stats[1][tid];
    float M = fmaxf(a.x, b.x);
    float S = a.y * __expf(a.x - M) + b.y * __expf(b.x - M);
    partial[(size_t)(m0 + tid) * VCH + v] = make_float2(M, S);
  }
#undef QUAD
}

// ---------------------------------------------------------------------------
// Fallback (round-1 kernel, fp32 inputs direct): used only if ws too small.
// ---------------------------------------------------------------------------
__global__ __launch_bounds__(256, 2) void lmhead_partial_fb(
    const float* __restrict__ x, const float* __restrict__ w,
    const int* __restrict__ tgt,
    float2* __restrict__ partial, float* __restrict__ tlogit)
{
  __shared__ uint4 xs[FB_B * 64 * 2 / 16];
  __shared__ uint4 wtl[FB_B * 64 * 2 / 16];
  __shared__ float2 stats[2][FB_B];

  const int bid = blockIdx.x;
  const int v = bid >> 5;
  const int r = bid & 31;
  const int v0 = v * FB_B;
  const int m0 = r * FB_B;
  const int tid = threadIdx.x;
  const int lane = tid & 63;
  const int wid = tid >> 6;
  const int wn = wid >> 1, wmm = wid & 1;
  const int lr = lane & 15, lk = lane >> 4;

  f32x4 acc[4][4];
  #pragma unroll
  for (int i = 0; i < 4; ++i)
    #pragma unroll
    for (int j = 0; j < 4; ++j) acc[i][j] = (f32x4)0.f;

  char* xsb = (char*)xs;
  char* wtb = (char*)wtl;

  for (int kt = 0; kt < DDIM / 64; ++kt) {
    const int k0 = kt * 64;
    __syncthreads();
    #pragma unroll
    for (int i = 0; i < 4; ++i) {
      int t = tid + i * 256;
      int m = t >> 3, kg = t & 7;
      const float* gp = x + (size_t)(m0 + m) * DDIM + k0 + kg * 8;
      float4 f0 = *(const float4*)gp;
      float4 f1 = *(const float4*)(gp + 4);
      uint4 pk;
      pk.x = pack2bf(f0.x, f0.y); pk.y = pack2bf(f0.z, f0.w);
      pk.z = pack2bf(f1.x, f1.y); pk.w = pack2bf(f1.z, f1.w);
      int byte = (m * 128 + kg * 16) ^ ((m & 7) << 4);
      *(uint4*)(xsb + byte) = pk;
    }
    #pragma unroll
    for (int i = 0; i < 4; ++i) {
      int t = tid + i * 256;
      int n = t & 127, kg = t >> 7;
      int col = v0 + n;
      float f[8];
      if (col < VOCAB) {
        const float* gp = w + (size_t)(k0 + kg * 8) * VOCAB + col;
        #pragma unroll
        for (int kk = 0; kk < 8; ++kk) f[kk] = gp[(size_t)kk * VOCAB];
      } else {
        #pragma unroll
        for (int kk = 0; kk < 8; ++kk) f[kk] = 0.f;
      }
      uint4 pk;
      pk.x = pack2bf(f[0], f[1]); pk.y = pack2bf(f[2], f[3]);
      pk.z = pack2bf(f[4], f[5]); pk.w = pack2bf(f[6], f[7]);
      int byte = (n * 128 + kg * 16) ^ ((n & 7) << 4);
      *(uint4*)(wtb + byte) = pk;
    }
    __syncthreads();
    #pragma unroll
    for (int ks = 0; ks < 2; ++ks) {
      bf16x8 af[4], bfr[4];
      #pragma unroll
      for (int bi = 0; bi < 4; ++bi) {
        int row = wn * 64 + bi * 16 + lr;
        int byte = (row * 128 + ks * 64 + lk * 16) ^ ((row & 7) << 4);
        af[bi] = *(const bf16x8*)(wtb + byte);
      }
      #pragma unroll
      for (int bj = 0; bj < 4; ++bj) {
        int row = wmm * 64 + bj * 16 + lr;
        int byte = (row * 128 + ks * 64 + lk * 16) ^ ((row & 7) << 4);
        bfr[bj] = *(const bf16x8*)(xsb + byte);
      }
      #pragma unroll
      for (int bi = 0; bi < 4; ++bi)
        #pragma unroll
        for (int bj = 0; bj < 4; ++bj)
          acc[bi][bj] = __builtin_amdgcn_mfma_f32_16x16x32_bf16(
              af[bi], bfr[bj], acc[bi][bj], 0, 0, 0);
    }
  }

  #pragma unroll
  for (int bj = 0; bj < 4; ++bj) {
    const int m_g = m0 + wmm * 64 + bj * 16 + lr;
    float vmax = -INFINITY;
    #pragma unroll
    for (int bi = 0; bi < 4; ++bi)
      #pragma unroll
      for (int rg = 0; rg < 4; ++rg) {
        int n_g = v0 + wn * 64 + bi * 16 + lk * 4 + rg;
        if (n_g < VOCAB) vmax = fmaxf(vmax, acc[bi][bj][rg]);
      }
    vmax = fmaxf(vmax, __shfl_xor(vmax, 16, 64));
    vmax = fmaxf(vmax, __shfl_xor(vmax, 32, 64));
    float ssum = 0.f;
    const int t = tgt[m_g];
    #pragma unroll
    for (int bi = 0; bi < 4; ++bi)
      #pragma unroll
      for (int rg = 0; rg < 4; ++rg) {
        int n_g = v0 + wn * 64 + bi * 16 + lk * 4 + rg;
        float val = acc[bi][bj][rg];
        if (n_g < VOCAB) ssum += __expf(val - vmax);
        if (n_g == t) tlogit[m_g] = val;
      }
    ssum += __shfl_xor(ssum, 16, 64);
    ssum += __shfl_xor(ssum, 32, 64);
    if (lk == 0) stats[wn][wmm * 64 + bj * 16 + lr] = make_float2(vmax, ssum);
  }
  __syncthreads();
  if (tid < FB_B) {
    float2 a = stats[0][tid], b = stats[1][tid];
    float M = fmaxf(a.x, b.x);
    float S = a.y * __expf(a.x - M) + b.y * __expf(b.x - M);
    partial[(size_t)(m0 + tid) * FB_VCH + v] = make_float2(M, S);
  }
}

// ---------------------------------------------------------------------------
// Reduce: per-row merge of nch chunk partials -> lse; loss sum into out[0].
// ---------------------------------------------------------------------------
__device__ __forceinline__ void lse_merge(float& m, float& s, float M, float S) {
  if (S > 0.f) {
    if (M > m) { s = s * __expf(m - M) + S; m = M; }
    else       { s += S * __expf(M - m); }
  }
}

__global__ void lmhead_reduce(const float2* __restrict__ partial,
                              const float* __restrict__ tlogit,
                              const int* __restrict__ tgt,
                              float* __restrict__ out, int nch)
{
  const int wid = threadIdx.x >> 6;
  const int lane = threadIdx.x & 63;
  const int row = blockIdx.x * 4 + wid;
  float m = -INFINITY, s = 0.f;
  for (int c = lane; c < nch; c += 64) {
    float2 p = partial[(size_t)row * nch + c];
    lse_merge(m, s, p.x, p.y);
  }
  #pragma unroll
  for (int off = 1; off < 64; off <<= 1) {
    float M = __shfl_xor(m, off, 64);
    float S = __shfl_xor(s, off, 64);
    lse_merge(m, s, M, S);
  }
  if (lane == 0) {
    int t = tgt[row];
    if (t != IGNORE_INDEX) {
      float loss = m + __logf(s) - tlogit[row];
      atomicAdd(out, loss);
    }
  }
}

extern "C" void kernel_launch(void* const* d_in, const int* in_sizes, int n_in,
                              void* d_out, int out_size, void* d_ws, size_t ws_size,
                              hipStream_t stream) {
  const float* x = (const float*)d_in[0];
  const float* w = (const float*)d_in[1];
  const int* tgt = (const int*)d_in[2];
  float* out = (float*)d_out;

  const size_t wt_bytes = (size_t)VP * DDIM * 2;          // ~206.6 MB
  const size_t xb_bytes = (size_t)N_TOK * DDIM * 2;       // 16.8 MB
  const size_t part_bytes = (size_t)N_TOK * VCH * 8;      // 6.5 MB
  const size_t tl_bytes = (size_t)N_TOK * 4;
  const size_t need = wt_bytes + xb_bytes + part_bytes + tl_bytes;  // ~229.8 MB

  hipMemsetAsync(d_out, 0, sizeof(float), stream);

  if (ws_size >= need) {
    ushort* wt = (ushort*)d_ws;
    ushort* xb = (ushort*)((char*)d_ws + wt_bytes);
    float2* partial = (float2*)((char*)d_ws + wt_bytes + xb_bytes);
    float* tlogit = (float*)((char*)d_ws + wt_bytes + xb_bytes + part_bytes);

    convert_x<<<dim3(N_TOK * DDIM / 8 / 256), 256, 0, stream>>>(x, xb);
    transpose_w<<<dim3(VP / 64, DDIM / 64), 256, 0, stream>>>(w, wt);
    lmhead8<<<dim3(VCH * RT), 512, 0, stream>>>(wt, xb, tgt, partial, tlogit);
    lmhead_reduce<<<dim3(N_TOK / 4), 256, 0, stream>>>(partial, tlogit, tgt, out, VCH);
  } else {
    float2* partial = (float2*)d_ws;
    float* tlogit = (float*)((char*)d_ws + (size_t)N_TOK * FB_VCH * 8);
    lmhead_partial_fb<<<dim3(FB_VCH * FB_RT), 256, 0, stream>>>(x, w, tgt, partial, tlogit);
    lmhead_reduce<<<dim3(N_TOK / 4), 256, 0, stream>>>(partial, tlogit, tgt, out, FB_VCH);
  }
}